// Round 15
// baseline (99.876 us; speedup 1.0000x reference)
//
#include <hip/hip_runtime.h>

#define BT    192
#define NNODE 512
#define DIM   128
#define NH    4
#define DH    32
#define NE    4096
#define NROWS (BT * NNODE)
#define GEMM_BLOCKS (NROWS / 128)   // 1536

typedef __attribute__((ext_vector_type(8))) short  short8b;
typedef __attribute__((ext_vector_type(4))) float  floatx4;
typedef __attribute__((ext_vector_type(8))) unsigned short ushort8;

__device__ inline unsigned short f2bf(float f) {
    unsigned int u = __float_as_uint(f);
    return (unsigned short)((u + 0x7FFFu + ((u >> 16) & 1u)) >> 16);
}
__device__ inline float bflo(unsigned int v) { return __uint_as_float(v << 16); }
__device__ inline float bfhi(unsigned int v) { return __uint_as_float(v & 0xFFFF0000u); }

__device__ inline short8b pack8(float4 a, float4 b) {
    short8b r;
    r[0] = (short)f2bf(a.x); r[1] = (short)f2bf(a.y);
    r[2] = (short)f2bf(a.z); r[3] = (short)f2bf(a.w);
    r[4] = (short)f2bf(b.x); r[5] = (short)f2bf(b.y);
    r[6] = (short)f2bf(b.z); r[7] = (short)f2bf(b.w);
    return r;
}

#define EDGE_ACC(hrow, sx, p) do {                                   \
    _Pragma("unroll")                                                \
    for (int j = 0; j < 4; ++j) {                                    \
        uint4 v = *(const uint4*)&(hrow)[(j ^ (sx)) * 4];            \
        int d0 = j * 8;                                              \
        acc[d0+0] = fmaf((p), bflo(v.x), acc[d0+0]);                 \
        acc[d0+1] = fmaf((p), bfhi(v.x), acc[d0+1]);                 \
        acc[d0+2] = fmaf((p), bflo(v.y), acc[d0+2]);                 \
        acc[d0+3] = fmaf((p), bfhi(v.y), acc[d0+3]);                 \
        acc[d0+4] = fmaf((p), bflo(v.z), acc[d0+4]);                 \
        acc[d0+5] = fmaf((p), bfhi(v.z), acc[d0+5]);                 \
        acc[d0+6] = fmaf((p), bflo(v.w), acc[d0+6]);                 \
        acc[d0+7] = fmaf((p), bfhi(v.w), acc[d0+7]);                 \
    } } while (0)

// ---------------------------------------------------------------------------
// K0: W pre-swizzle only (8 blocks x 512). Must precede the GEMM.
// ---------------------------------------------------------------------------
__global__ __launch_bounds__(512) void wswz_k(
    const float* __restrict__ W, unsigned short* __restrict__ wswz)
{
    int j = blockIdx.x * 512 + threadIdx.x;      // float4 index, 4096 total
    const float4* W4 = (const float4*)W;
    float4 wv = W4[j];
    int k = j >> 5, c4 = (j & 31) * 4;
    float vv[4] = { wv.x, wv.y, wv.z, wv.w };
#pragma unroll
    for (int e = 0; e < 4; ++e) {
        int col = c4 + e;
        int byte = col * 256 + ((2 * k) ^ ((col & 7) << 4));
        wswz[byte >> 1] = f2bf(vv[e]);
    }
}

// ---------------------------------------------------------------------------
// K1: bf16 MFMA GEMM + score epilogue (blocks 0..1535, unchanged math)
//     PLUS the CSR build folded in as blocks 1536..1599 (256-thr variant,
//     LDS aliased into sm) so its ~5us hides under the GEMM.
// ---------------------------------------------------------------------------
__global__ __launch_bounds__(256) void gemm_mfma_k(
    const float* __restrict__ x, const unsigned short* __restrict__ wswz,
    const float* __restrict__ att_src, const float* __restrict__ att_dst,
    unsigned short* __restrict__ h, float* __restrict__ ssg,
    float* __restrict__ sdg,
    const int* __restrict__ ei, const float* __restrict__ ew,
    int* __restrict__ rp2, int* __restrict__ cs2,
    float* __restrict__ ce2, int* __restrict__ perm)
{
    __shared__ __align__(16) char sm[64 * 132 * 4];   // 33792 B
    __shared__ float att_f[256];
    int t = threadIdx.x;

    if (blockIdx.x >= GEMM_BLOCKS) {
        // ================= CSR build path (64 blocks, 256 threads) =========
        int* dsts   = (int*)sm;                 // 16384 B
        int* cnt    = (int*)(sm + 16384);       // 2048
        int* scn    = (int*)(sm + 18432);       // 2048
        int* nodeAt = (int*)(sm + 20480);       // 2048
        int* hist   = (int*)(sm + 22528);       // 1024
        int* hscan  = (int*)(sm + 23552);       // 1024
        int cb = blockIdx.x - GEMM_BLOCKS;
        int i0 = t, i1 = t + 256;

        for (int e = t; e < NE; e += 256) dsts[e] = ei[NE + e];
        cnt[i0] = 0; cnt[i1] = 0;
        hist[t] = 0;
        __syncthreads();
        for (int e = t; e < NE; e += 256) atomicAdd(&cnt[dsts[e]], 1);
        __syncthreads();

        int deg0 = cnt[i0], deg1 = cnt[i1];
        int b0 = (deg0 < 255) ? deg0 : 255;
        int b1 = (deg1 < 255) ? deg1 : 255;
        atomicAdd(&hist[b0], 1);
        atomicAdd(&hist[b1], 1);
        __syncthreads();
        hscan[t] = hist[t];
        __syncthreads();
        for (int o = 1; o < 256; o <<= 1) {
            int v = (t >= o) ? hscan[t - o] : 0;
            __syncthreads();
            hscan[t] += v;
            __syncthreads();
        }
        int off0 = 0, off1 = 0;
        for (int n = 0; n < i0; ++n) {
            int dn = cnt[n]; dn = (dn < 255) ? dn : 255;
            off0 += (dn == b0) ? 1 : 0;
        }
        for (int n = 0; n < i1; ++n) {
            int dn = cnt[n]; dn = (dn < 255) ? dn : 255;
            off1 += (dn == b1) ? 1 : 0;
        }
        int rank0 = hscan[b0] - hist[b0] + off0;
        int rank1 = hscan[b1] - hist[b1] + off1;
        nodeAt[rank0] = i0;
        nodeAt[rank1] = i1;
        __syncthreads();

        scn[i0] = cnt[nodeAt[i0]];
        scn[i1] = cnt[nodeAt[i1]];
        __syncthreads();
        for (int o = 1; o < NNODE; o <<= 1) {
            int v0 = (i0 >= o) ? scn[i0 - o] : 0;
            int v1 = (i1 >= o) ? scn[i1 - o] : 0;
            __syncthreads();
            scn[i0] += v0; scn[i1] += v1;
            __syncthreads();
        }
        if (cb == 0) {
            if (t == 0) rp2[0] = 0;
            rp2[i0 + 1] = scn[i0];
            rp2[i1 + 1] = scn[i1];
            perm[i0] = nodeAt[i0];
            perm[i1] = nodeAt[i1];
        }
        __syncthreads();

        int wave = t >> 6, lane = t & 63;
#pragma unroll
        for (int rr = 0; rr < 2; ++rr) {
            int r = cb * 8 + rr * 4 + wave;
            int node = nodeAt[r];
            int pos = scn[r] - cnt[node];
            for (int c = 0; c < NE; c += 64) {
                int e = c + lane;
                int d = dsts[e];
                unsigned long long mask = __ballot(d == node);
                if (d == node) {
                    int ofs = __popcll(mask & ((1ull << lane) - 1ull));
                    cs2[pos + ofs] = ei[e];
                    ce2[pos + ofs] = ew[e];
                }
                pos += __popcll(mask);
            }
        }
        return;
    }

    // ================= GEMM path (blocks 0..1535, unchanged) ===============
    if (t < 128) att_f[t] = att_src[(t & 3) * 32 + (t >> 2)];
    else         att_f[t] = att_dst[(t & 3) * 32 + ((t - 128) >> 2)];
    {
        const uint4* g = (const uint4*)wswz;
        uint4* ld = (uint4*)sm;
#pragma unroll
        for (int i = 0; i < 8; ++i) ld[t + i * 256] = g[t + i * 256];
    }
    int w = t >> 6, l = t & 63, lr = l & 15, lk = l >> 4;
    size_t base = (size_t)blockIdx.x * 128;
    const float* xA = x + (base + (size_t)w * 16 + lr) * DIM;
    const float* xB = xA + 64 * DIM;

    floatx4 accA[8], accB[8];
#pragma unroll
    for (int n = 0; n < 8; ++n) {
        accA[n] = (floatx4){0.f, 0.f, 0.f, 0.f};
        accB[n] = (floatx4){0.f, 0.f, 0.f, 0.f};
    }
    __syncthreads();

#pragma unroll
    for (int kk = 0; kk < 4; ++kk) {
        int k0 = kk * 32 + lk * 8;
        float4 a0 = *(const float4*)(xA + k0);
        float4 a1 = *(const float4*)(xA + k0 + 4);
        float4 b0 = *(const float4*)(xB + k0);
        float4 b1 = *(const float4*)(xB + k0 + 4);
        short8b av = pack8(a0, a1);
        short8b bv = pack8(b0, b1);
        int c = kk * 4 + lk;
#pragma unroll
        for (int n = 0; n < 8; ++n) {
            int col = n * 16 + lr;
            short8b bf = *(const short8b*)(sm + col * 256 + ((c ^ (col & 7)) << 4));
            accA[n] = __builtin_amdgcn_mfma_f32_16x16x32_bf16(av, bf, accA[n], 0, 0, 0);
            accB[n] = __builtin_amdgcn_mfma_f32_16x16x32_bf16(bv, bf, accB[n], 0, 0, 0);
        }
    }

    float* Ct = (float*)sm;
    unsigned short* hbase = h + base * DIM;
    int sr = t >> 2, sq = t & 3;

    // pass A: rows 0..63
    __syncthreads();
#pragma unroll
    for (int n = 0; n < 8; ++n)
#pragma unroll
        for (int j = 0; j < 4; ++j)
            Ct[(w * 16 + lk * 4 + j) * 132 + n * 16 + lr] = accA[n][j];
    __syncthreads();
#pragma unroll
    for (int i = 0; i < 4; ++i) {
        int chunk = t + i * 256;
        int row = chunk >> 4, cc = chunk & 15;
        const float* cp = Ct + row * 132 + cc * 8;
        ushort8 v;
#pragma unroll
        for (int e = 0; e < 8; ++e) v[e] = f2bf(cp[e]);
        *(ushort8*)(hbase + row * DIM + cc * 8) = v;
    }
    {
        const float* cp = Ct + sr * 132 + sq * 32;
        float ps = 0.f, pd = 0.f;
#pragma unroll
        for (int j = 0; j < 32; j += 4) {
            float4 cv = *(const float4*)(cp + j);
            ps = fmaf(cv.x, att_f[(j+0)*4 + sq], ps);
            ps = fmaf(cv.y, att_f[(j+1)*4 + sq], ps);
            ps = fmaf(cv.z, att_f[(j+2)*4 + sq], ps);
            ps = fmaf(cv.w, att_f[(j+3)*4 + sq], ps);
            pd = fmaf(cv.x, att_f[128 + (j+0)*4 + sq], pd);
            pd = fmaf(cv.y, att_f[128 + (j+1)*4 + sq], pd);
            pd = fmaf(cv.z, att_f[128 + (j+2)*4 + sq], pd);
            pd = fmaf(cv.w, att_f[128 + (j+3)*4 + sq], pd);
        }
        size_t grow = base + sr;
        ssg[grow * 4 + sq] = ps;
        sdg[grow * 4 + sq] = pd;
    }

    // pass B: rows 64..127
    __syncthreads();
#pragma unroll
    for (int n = 0; n < 8; ++n)
#pragma unroll
        for (int j = 0; j < 4; ++j)
            Ct[(w * 16 + lk * 4 + j) * 132 + n * 16 + lr] = accB[n][j];
    __syncthreads();
#pragma unroll
    for (int i = 0; i < 4; ++i) {
        int chunk = t + i * 256;
        int row = chunk >> 4, cc = chunk & 15;
        const float* cp = Ct + row * 132 + cc * 8;
        ushort8 v;
#pragma unroll
        for (int e = 0; e < 8; ++e) v[e] = f2bf(cp[e]);
        *(ushort8*)(hbase + (64 + row) * DIM + cc * 8) = v;
    }
    {
        const float* cp = Ct + sr * 132 + sq * 32;
        float ps = 0.f, pd = 0.f;
#pragma unroll
        for (int j = 0; j < 32; j += 4) {
            float4 cv = *(const float4*)(cp + j);
            ps = fmaf(cv.x, att_f[(j+0)*4 + sq], ps);
            ps = fmaf(cv.y, att_f[(j+1)*4 + sq], ps);
            ps = fmaf(cv.z, att_f[(j+2)*4 + sq], ps);
            ps = fmaf(cv.w, att_f[(j+3)*4 + sq], ps);
            pd = fmaf(cv.x, att_f[128 + (j+0)*4 + sq], pd);
            pd = fmaf(cv.y, att_f[128 + (j+1)*4 + sq], pd);
            pd = fmaf(cv.z, att_f[128 + (j+2)*4 + sq], pd);
            pd = fmaf(cv.w, att_f[128 + (j+3)*4 + sq], pd);
        }
        size_t grow = base + 64 + sr;
        ssg[grow * 4 + sq] = ps;
        sdg[grow * 4 + sq] = pd;
    }
}

// ---------------------------------------------------------------------------
// K2: fused gather-agg + softmax-normalize + bias + LayerNorm + ELU.
// r13 structure; edge loop now 4-WAY UNROLLED (16 ds_read_b128 + 4 exp
// chains in flight; VGPR ~95 < 128 so the LDS-capped 16 waves/CU hold).
// ---------------------------------------------------------------------------
__global__ __launch_bounds__(1024) void agg_ln_k(
    const unsigned short* __restrict__ h,
    const float* __restrict__ ssg, const float* __restrict__ sdg,
    const int* __restrict__ rp2, const int* __restrict__ cs2,
    const float* __restrict__ ce2, const int* __restrict__ perm,
    const float* __restrict__ bias, const float* __restrict__ gamma,
    const float* __restrict__ beta, float* __restrict__ out)
{
    __shared__ unsigned int hs[NH][NNODE * 16];   // 131072 B
    __shared__ float ssl[NNODE * NH];             // 8192 B
    __shared__ float prm[384];
    int t  = threadIdx.x;
    int bt = blockIdx.x;

    const uint4* hg = (const uint4*)(h + (size_t)bt * NNODE * DIM);
    for (int i = t; i < NNODE * 16; i += 1024) {
        int n = i >> 4, c = i & 15, hh = c >> 2, j = c & 3;
        uint4 v = hg[i];
        int js = j ^ ((n >> 1) & 3);
        *(uint4*)&hs[hh][n * 16 + js * 4] = v;
    }
    const float* ssgb = ssg + (size_t)bt * NNODE * NH;
    for (int i = t; i < NNODE * NH; i += 1024) ssl[i] = ssgb[i];
    if (t < 384) prm[t] = (t < 128) ? bias[t] : (t < 256) ? gamma[t - 128] : beta[t - 256];
    __syncthreads();

    int l  = t & 63, w = t >> 6;
    int hh = l >> 4, rl = l & 15;
    int g  = w * 16 + rl;                          // 0..255
    const float* sdgb = sdg + (size_t)bt * NNODE * NH;
    float* outb = out + (size_t)bt * NNODE * DIM;

#pragma unroll
    for (int pi = 0; pi < 2; ++pi) {
        int rank = pi ? (511 - g) : g;
        int node = perm[rank];
        int beg = rp2[rank], end = rp2[rank + 1];
        float sd = sdgb[node * 4 + hh];

        float acc[32];
#pragma unroll
        for (int d = 0; d < 32; ++d) acc[d] = 0.f;
        float den = 0.f;

        int e = beg;
        for (; e + 4 <= end; e += 4) {
            int   s0 = cs2[e],     s1 = cs2[e + 1];
            int   s2 = cs2[e + 2], s3 = cs2[e + 3];
            float w0 = ce2[e],     w1 = ce2[e + 1];
            float w2 = ce2[e + 2], w3 = ce2[e + 3];
            float a0 = ssl[s0 * 4 + hh] + sd; a0 = (a0 > 0.f) ? a0 : 0.2f * a0;
            float a1 = ssl[s1 * 4 + hh] + sd; a1 = (a1 > 0.f) ? a1 : 0.2f * a1;
            float a2 = ssl[s2 * 4 + hh] + sd; a2 = (a2 > 0.f) ? a2 : 0.2f * a2;
            float a3 = ssl[s3 * 4 + hh] + sd; a3 = (a3 > 0.f) ? a3 : 0.2f * a3;
            float p0 = __expf(a0 * w0);
            float p1 = __expf(a1 * w1);
            float p2 = __expf(a2 * w2);
            float p3 = __expf(a3 * w3);
            den += p0; den += p1; den += p2; den += p3;
            const unsigned int* r0 = &hs[hh][s0 * 16];
            const unsigned int* r1 = &hs[hh][s1 * 16];
            const unsigned int* r2 = &hs[hh][s2 * 16];
            const unsigned int* r3 = &hs[hh][s3 * 16];
            int x0 = (s0 >> 1) & 3, x1 = (s1 >> 1) & 3;
            int x2 = (s2 >> 1) & 3, x3 = (s3 >> 1) & 3;
            EDGE_ACC(r0, x0, p0);
            EDGE_ACC(r1, x1, p1);
            EDGE_ACC(r2, x2, p2);
            EDGE_ACC(r3, x3, p3);
        }
        for (; e < end; ++e) {
            int   s0 = cs2[e];
            float w0 = ce2[e];
            float a0 = ssl[s0 * 4 + hh] + sd; a0 = (a0 > 0.f) ? a0 : 0.2f * a0;
            float p0 = __expf(a0 * w0);
            den += p0;
            const unsigned int* r0 = &hs[hh][s0 * 16];
            int x0 = (s0 >> 1) & 3;
            EDGE_ACC(r0, x0, p0);
        }

        float inv = 1.f / (den + 1e-16f);
        float s1 = 0.f, s2 = 0.f;
#pragma unroll
        for (int d = 0; d < 32; ++d) {
            float vv = fmaf(acc[d], inv, prm[hh * 32 + d]);
            acc[d] = vv;
            s1 += vv;
            s2 = fmaf(vv, vv, s2);
        }
        s1 += __shfl_xor(s1, 16, 64);
        s2 += __shfl_xor(s2, 16, 64);
        s1 += __shfl_xor(s1, 32, 64);
        s2 += __shfl_xor(s2, 32, 64);
        float mean = s1 * (1.f / 128.f);
        float var  = s2 * (1.f / 128.f) - mean * mean;
        float rstd = rsqrtf(var + 1e-5f);

        float* op = outb + (size_t)node * DIM + hh * 32;
#pragma unroll
        for (int d = 0; d < 32; d += 4) {
            int pd0 = 128 + hh * 32 + d, pb0 = 256 + hh * 32 + d;
            float y0 = (acc[d+0] - mean) * rstd * prm[pd0+0] + prm[pb0+0];
            float y1 = (acc[d+1] - mean) * rstd * prm[pd0+1] + prm[pb0+1];
            float y2 = (acc[d+2] - mean) * rstd * prm[pd0+2] + prm[pb0+2];
            float y3 = (acc[d+3] - mean) * rstd * prm[pd0+3] + prm[pb0+3];
            float4 o4;
            o4.x = (y0 > 0.f) ? y0 : expm1f(y0);
            o4.y = (y1 > 0.f) ? y1 : expm1f(y1);
            o4.z = (y2 > 0.f) ? y2 : expm1f(y2);
            o4.w = (y3 > 0.f) ? y3 : expm1f(y3);
            *(float4*)(op + d) = o4;
        }
    }
}

// ---------------------------------------------------------------------------
extern "C" void kernel_launch(void* const* d_in, const int* in_sizes, int n_in,
                              void* d_out, int out_size, void* d_ws, size_t ws_size,
                              hipStream_t stream)
{
    const float* x     = (const float*)d_in[0];
    const int*   ei    = (const int*)  d_in[1];
    const float* ew    = (const float*)d_in[2];
    const float* W     = (const float*)d_in[3];
    const float* asrc  = (const float*)d_in[4];
    const float* adst  = (const float*)d_in[5];
    const float* bias  = (const float*)d_in[6];
    const float* gamma = (const float*)d_in[7];
    const float* beta  = (const float*)d_in[8];
    float* out = (float*)d_out;

    char* ws = (char*)d_ws;
    unsigned short* h = (unsigned short*)ws;                 // 25 MB bf16
    size_t off = (size_t)NROWS * DIM * sizeof(unsigned short);
    unsigned short* wswz = (unsigned short*)(ws + off);      // 32 KB bf16 swizzled
    off += (size_t)DIM * DIM * sizeof(unsigned short);
    float* ssg = (float*)(ws + off);                         // 1.5 MB
    off += (size_t)NROWS * NH * sizeof(float);
    float* sdg = (float*)(ws + off);                         // 1.5 MB
    off += (size_t)NROWS * NH * sizeof(float);
    int* rp2 = (int*)(ws + off);
    off += (((NNODE + 1) * sizeof(int)) + 15) & ~(size_t)15;
    int* perm = (int*)(ws + off);
    off += (size_t)NNODE * sizeof(int);
    int* cs2 = (int*)(ws + off);
    off += (size_t)NE * sizeof(int);
    float* ce2 = (float*)(ws + off);
    off += (size_t)NE * sizeof(float);

    wswz_k<<<8, 512, 0, stream>>>(W, wswz);
    gemm_mfma_k<<<GEMM_BLOCKS + 64, 256, 0, stream>>>(
        x, wswz, asrc, adst, h, ssg, sdg, ei, ew, rp2, cs2, ce2, perm);
    agg_ln_k<<<BT, 1024, 0, stream>>>(h, ssg, sdg, rp2, cs2, ce2, perm,
                                      bias, gamma, beta, out);
}

// Round 16
// 99.730 us; speedup vs baseline: 1.0015x; 1.0015x over previous
//
#include <hip/hip_runtime.h>

#define BT    192
#define NNODE 512
#define DIM   128
#define NH    4
#define DH    32
#define NE    4096
#define NROWS (BT * NNODE)
#define GEMM_BLOCKS (NROWS / 128)   // 1536

typedef __attribute__((ext_vector_type(8))) short  short8b;
typedef __attribute__((ext_vector_type(4))) float  floatx4;
typedef __attribute__((ext_vector_type(8))) unsigned short ushort8;

__device__ inline unsigned short f2bf(float f) {
    unsigned int u = __float_as_uint(f);
    return (unsigned short)((u + 0x7FFFu + ((u >> 16) & 1u)) >> 16);
}
__device__ inline float bflo(unsigned int v) { return __uint_as_float(v << 16); }
__device__ inline float bfhi(unsigned int v) { return __uint_as_float(v & 0xFFFF0000u); }

__device__ inline short8b pack8(float4 a, float4 b) {
    short8b r;
    r[0] = (short)f2bf(a.x); r[1] = (short)f2bf(a.y);
    r[2] = (short)f2bf(a.z); r[3] = (short)f2bf(a.w);
    r[4] = (short)f2bf(b.x); r[5] = (short)f2bf(b.y);
    r[6] = (short)f2bf(b.z); r[7] = (short)f2bf(b.w);
    return r;
}

#define EDGE_ACC(hrow, sx, p) do {                                   \
    _Pragma("unroll")                                                \
    for (int j = 0; j < 4; ++j) {                                    \
        uint4 v = *(const uint4*)&(hrow)[(j ^ (sx)) * 4];            \
        int d0 = j * 8;                                              \
        acc[d0+0] = fmaf((p), bflo(v.x), acc[d0+0]);                 \
        acc[d0+1] = fmaf((p), bfhi(v.x), acc[d0+1]);                 \
        acc[d0+2] = fmaf((p), bflo(v.y), acc[d0+2]);                 \
        acc[d0+3] = fmaf((p), bfhi(v.y), acc[d0+3]);                 \
        acc[d0+4] = fmaf((p), bflo(v.z), acc[d0+4]);                 \
        acc[d0+5] = fmaf((p), bfhi(v.z), acc[d0+5]);                 \
        acc[d0+6] = fmaf((p), bflo(v.w), acc[d0+6]);                 \
        acc[d0+7] = fmaf((p), bfhi(v.w), acc[d0+7]);                 \
    } } while (0)

// ---------------------------------------------------------------------------
// K0: W pre-swizzle only (8 blocks x 512). Must precede the GEMM.
// ---------------------------------------------------------------------------
__global__ __launch_bounds__(512) void wswz_k(
    const float* __restrict__ W, unsigned short* __restrict__ wswz)
{
    int j = blockIdx.x * 512 + threadIdx.x;      // float4 index, 4096 total
    const float4* W4 = (const float4*)W;
    float4 wv = W4[j];
    int k = j >> 5, c4 = (j & 31) * 4;
    float vv[4] = { wv.x, wv.y, wv.z, wv.w };
#pragma unroll
    for (int e = 0; e < 4; ++e) {
        int col = c4 + e;
        int byte = col * 256 + ((2 * k) ^ ((col & 7) << 4));
        wswz[byte >> 1] = f2bf(vv[e]);
    }
}

// ---------------------------------------------------------------------------
// K1: bf16 MFMA GEMM + score epilogue (blocks 0..1535) + CSR build folded
// in as blocks 1536..1599 (runs concurrently; agg consumes both afterward).
// ---------------------------------------------------------------------------
__global__ __launch_bounds__(256) void gemm_mfma_k(
    const float* __restrict__ x, const unsigned short* __restrict__ wswz,
    const float* __restrict__ att_src, const float* __restrict__ att_dst,
    unsigned short* __restrict__ h, float* __restrict__ ssg,
    float* __restrict__ sdg,
    const int* __restrict__ ei, const float* __restrict__ ew,
    int* __restrict__ rp2, int* __restrict__ cs2,
    float* __restrict__ ce2, int* __restrict__ perm)
{
    __shared__ __align__(16) char sm[64 * 132 * 4];   // 33792 B
    __shared__ float att_f[256];
    int t = threadIdx.x;

    if (blockIdx.x >= GEMM_BLOCKS) {
        // ================= CSR build path (64 blocks, 256 threads) =========
        int* dsts   = (int*)sm;                 // 16384 B
        int* cnt    = (int*)(sm + 16384);       // 2048
        int* scn    = (int*)(sm + 18432);       // 2048
        int* nodeAt = (int*)(sm + 20480);       // 2048
        int* hist   = (int*)(sm + 22528);       // 1024
        int* hscan  = (int*)(sm + 23552);       // 1024
        int cb = blockIdx.x - GEMM_BLOCKS;
        int i0 = t, i1 = t + 256;

        for (int e = t; e < NE; e += 256) dsts[e] = ei[NE + e];
        cnt[i0] = 0; cnt[i1] = 0;
        hist[t] = 0;
        __syncthreads();
        for (int e = t; e < NE; e += 256) atomicAdd(&cnt[dsts[e]], 1);
        __syncthreads();

        int deg0 = cnt[i0], deg1 = cnt[i1];
        int b0 = (deg0 < 255) ? deg0 : 255;
        int b1 = (deg1 < 255) ? deg1 : 255;
        atomicAdd(&hist[b0], 1);
        atomicAdd(&hist[b1], 1);
        __syncthreads();
        hscan[t] = hist[t];
        __syncthreads();
        for (int o = 1; o < 256; o <<= 1) {
            int v = (t >= o) ? hscan[t - o] : 0;
            __syncthreads();
            hscan[t] += v;
            __syncthreads();
        }
        int off0 = 0, off1 = 0;
        for (int n = 0; n < i0; ++n) {
            int dn = cnt[n]; dn = (dn < 255) ? dn : 255;
            off0 += (dn == b0) ? 1 : 0;
        }
        for (int n = 0; n < i1; ++n) {
            int dn = cnt[n]; dn = (dn < 255) ? dn : 255;
            off1 += (dn == b1) ? 1 : 0;
        }
        int rank0 = hscan[b0] - hist[b0] + off0;
        int rank1 = hscan[b1] - hist[b1] + off1;
        nodeAt[rank0] = i0;
        nodeAt[rank1] = i1;
        __syncthreads();

        scn[i0] = cnt[nodeAt[i0]];
        scn[i1] = cnt[nodeAt[i1]];
        __syncthreads();
        for (int o = 1; o < NNODE; o <<= 1) {
            int v0 = (i0 >= o) ? scn[i0 - o] : 0;
            int v1 = (i1 >= o) ? scn[i1 - o] : 0;
            __syncthreads();
            scn[i0] += v0; scn[i1] += v1;
            __syncthreads();
        }
        if (cb == 0) {
            if (t == 0) rp2[0] = 0;
            rp2[i0 + 1] = scn[i0];
            rp2[i1 + 1] = scn[i1];
            perm[i0] = nodeAt[i0];
            perm[i1] = nodeAt[i1];
        }
        __syncthreads();

        int wave = t >> 6, lane = t & 63;
#pragma unroll
        for (int rr = 0; rr < 2; ++rr) {
            int r = cb * 8 + rr * 4 + wave;
            int node = nodeAt[r];
            int pos = scn[r] - cnt[node];
            for (int c = 0; c < NE; c += 64) {
                int e = c + lane;
                int d = dsts[e];
                unsigned long long mask = __ballot(d == node);
                if (d == node) {
                    int ofs = __popcll(mask & ((1ull << lane) - 1ull));
                    cs2[pos + ofs] = ei[e];
                    ce2[pos + ofs] = ew[e];
                }
                pos += __popcll(mask);
            }
        }
        return;
    }

    // ================= GEMM path (blocks 0..1535, unchanged) ===============
    if (t < 128) att_f[t] = att_src[(t & 3) * 32 + (t >> 2)];
    else         att_f[t] = att_dst[(t & 3) * 32 + ((t - 128) >> 2)];
    {
        const uint4* g = (const uint4*)wswz;
        uint4* ld = (uint4*)sm;
#pragma unroll
        for (int i = 0; i < 8; ++i) ld[t + i * 256] = g[t + i * 256];
    }
    int w = t >> 6, l = t & 63, lr = l & 15, lk = l >> 4;
    size_t base = (size_t)blockIdx.x * 128;
    const float* xA = x + (base + (size_t)w * 16 + lr) * DIM;
    const float* xB = xA + 64 * DIM;

    floatx4 accA[8], accB[8];
#pragma unroll
    for (int n = 0; n < 8; ++n) {
        accA[n] = (floatx4){0.f, 0.f, 0.f, 0.f};
        accB[n] = (floatx4){0.f, 0.f, 0.f, 0.f};
    }
    __syncthreads();

#pragma unroll
    for (int kk = 0; kk < 4; ++kk) {
        int k0 = kk * 32 + lk * 8;
        float4 a0 = *(const float4*)(xA + k0);
        float4 a1 = *(const float4*)(xA + k0 + 4);
        float4 b0 = *(const float4*)(xB + k0);
        float4 b1 = *(const float4*)(xB + k0 + 4);
        short8b av = pack8(a0, a1);
        short8b bv = pack8(b0, b1);
        int c = kk * 4 + lk;
#pragma unroll
        for (int n = 0; n < 8; ++n) {
            int col = n * 16 + lr;
            short8b bf = *(const short8b*)(sm + col * 256 + ((c ^ (col & 7)) << 4));
            accA[n] = __builtin_amdgcn_mfma_f32_16x16x32_bf16(av, bf, accA[n], 0, 0, 0);
            accB[n] = __builtin_amdgcn_mfma_f32_16x16x32_bf16(bv, bf, accB[n], 0, 0, 0);
        }
    }

    float* Ct = (float*)sm;
    unsigned short* hbase = h + base * DIM;
    int sr = t >> 2, sq = t & 3;

    // pass A: rows 0..63
    __syncthreads();
#pragma unroll
    for (int n = 0; n < 8; ++n)
#pragma unroll
        for (int j = 0; j < 4; ++j)
            Ct[(w * 16 + lk * 4 + j) * 132 + n * 16 + lr] = accA[n][j];
    __syncthreads();
#pragma unroll
    for (int i = 0; i < 4; ++i) {
        int chunk = t + i * 256;
        int row = chunk >> 4, cc = chunk & 15;
        const float* cp = Ct + row * 132 + cc * 8;
        ushort8 v;
#pragma unroll
        for (int e = 0; e < 8; ++e) v[e] = f2bf(cp[e]);
        *(ushort8*)(hbase + row * DIM + cc * 8) = v;
    }
    {
        const float* cp = Ct + sr * 132 + sq * 32;
        float ps = 0.f, pd = 0.f;
#pragma unroll
        for (int j = 0; j < 32; j += 4) {
            float4 cv = *(const float4*)(cp + j);
            ps = fmaf(cv.x, att_f[(j+0)*4 + sq], ps);
            ps = fmaf(cv.y, att_f[(j+1)*4 + sq], ps);
            ps = fmaf(cv.z, att_f[(j+2)*4 + sq], ps);
            ps = fmaf(cv.w, att_f[(j+3)*4 + sq], ps);
            pd = fmaf(cv.x, att_f[128 + (j+0)*4 + sq], pd);
            pd = fmaf(cv.y, att_f[128 + (j+1)*4 + sq], pd);
            pd = fmaf(cv.z, att_f[128 + (j+2)*4 + sq], pd);
            pd = fmaf(cv.w, att_f[128 + (j+3)*4 + sq], pd);
        }
        size_t grow = base + sr;
        ssg[grow * 4 + sq] = ps;
        sdg[grow * 4 + sq] = pd;
    }

    // pass B: rows 64..127
    __syncthreads();
#pragma unroll
    for (int n = 0; n < 8; ++n)
#pragma unroll
        for (int j = 0; j < 4; ++j)
            Ct[(w * 16 + lk * 4 + j) * 132 + n * 16 + lr] = accB[n][j];
    __syncthreads();
#pragma unroll
    for (int i = 0; i < 4; ++i) {
        int chunk = t + i * 256;
        int row = chunk >> 4, cc = chunk & 15;
        const float* cp = Ct + row * 132 + cc * 8;
        ushort8 v;
#pragma unroll
        for (int e = 0; e < 8; ++e) v[e] = f2bf(cp[e]);
        *(ushort8*)(hbase + (64 + row) * DIM + cc * 8) = v;
    }
    {
        const float* cp = Ct + sr * 132 + sq * 32;
        float ps = 0.f, pd = 0.f;
#pragma unroll
        for (int j = 0; j < 32; j += 4) {
            float4 cv = *(const float4*)(cp + j);
            ps = fmaf(cv.x, att_f[(j+0)*4 + sq], ps);
            ps = fmaf(cv.y, att_f[(j+1)*4 + sq], ps);
            ps = fmaf(cv.z, att_f[(j+2)*4 + sq], ps);
            ps = fmaf(cv.w, att_f[(j+3)*4 + sq], ps);
            pd = fmaf(cv.x, att_f[128 + (j+0)*4 + sq], pd);
            pd = fmaf(cv.y, att_f[128 + (j+1)*4 + sq], pd);
            pd = fmaf(cv.z, att_f[128 + (j+2)*4 + sq], pd);
            pd = fmaf(cv.w, att_f[128 + (j+3)*4 + sq], pd);
        }
        size_t grow = base + 64 + sr;
        ssg[grow * 4 + sq] = ps;
        sdg[grow * 4 + sq] = pd;
    }
}

// ---------------------------------------------------------------------------
// K2: fused gather-agg + softmax-normalize + bias + LayerNorm + ELU.
// r13 structure; 4-WAY edge unroll. __launch_bounds__(1024, 4) declares the
// true occupancy (1 block/CU, LDS-capped) so the register allocator gets a
// 128-VGPR budget instead of assuming 64 and spilling (r14's failure mode).
// ---------------------------------------------------------------------------
__global__ __launch_bounds__(1024, 4) void agg_ln_k(
    const unsigned short* __restrict__ h,
    const float* __restrict__ ssg, const float* __restrict__ sdg,
    const int* __restrict__ rp2, const int* __restrict__ cs2,
    const float* __restrict__ ce2, const int* __restrict__ perm,
    const float* __restrict__ bias, const float* __restrict__ gamma,
    const float* __restrict__ beta, float* __restrict__ out)
{
    __shared__ unsigned int hs[NH][NNODE * 16];   // 131072 B
    __shared__ float ssl[NNODE * NH];             // 8192 B
    __shared__ float prm[384];
    int t  = threadIdx.x;
    int bt = blockIdx.x;

    const uint4* hg = (const uint4*)(h + (size_t)bt * NNODE * DIM);
    for (int i = t; i < NNODE * 16; i += 1024) {
        int n = i >> 4, c = i & 15, hh = c >> 2, j = c & 3;
        uint4 v = hg[i];
        int js = j ^ ((n >> 1) & 3);
        *(uint4*)&hs[hh][n * 16 + js * 4] = v;
    }
    const float* ssgb = ssg + (size_t)bt * NNODE * NH;
    for (int i = t; i < NNODE * NH; i += 1024) ssl[i] = ssgb[i];
    if (t < 384) prm[t] = (t < 128) ? bias[t] : (t < 256) ? gamma[t - 128] : beta[t - 256];
    __syncthreads();

    int l  = t & 63, w = t >> 6;
    int hh = l >> 4, rl = l & 15;
    int g  = w * 16 + rl;                          // 0..255
    const float* sdgb = sdg + (size_t)bt * NNODE * NH;
    float* outb = out + (size_t)bt * NNODE * DIM;

#pragma unroll
    for (int pi = 0; pi < 2; ++pi) {
        int rank = pi ? (511 - g) : g;
        int node = perm[rank];
        int beg = rp2[rank], end = rp2[rank + 1];
        float sd = sdgb[node * 4 + hh];

        float acc[32];
#pragma unroll
        for (int d = 0; d < 32; ++d) acc[d] = 0.f;
        float den = 0.f;

        int e = beg;
        for (; e + 4 <= end; e += 4) {
            int   s0 = cs2[e],     s1 = cs2[e + 1];
            int   s2 = cs2[e + 2], s3 = cs2[e + 3];
            float w0 = ce2[e],     w1 = ce2[e + 1];
            float w2 = ce2[e + 2], w3 = ce2[e + 3];
            float a0 = ssl[s0 * 4 + hh] + sd; a0 = (a0 > 0.f) ? a0 : 0.2f * a0;
            float a1 = ssl[s1 * 4 + hh] + sd; a1 = (a1 > 0.f) ? a1 : 0.2f * a1;
            float a2 = ssl[s2 * 4 + hh] + sd; a2 = (a2 > 0.f) ? a2 : 0.2f * a2;
            float a3 = ssl[s3 * 4 + hh] + sd; a3 = (a3 > 0.f) ? a3 : 0.2f * a3;
            float p0 = __expf(a0 * w0);
            float p1 = __expf(a1 * w1);
            float p2 = __expf(a2 * w2);
            float p3 = __expf(a3 * w3);
            den += p0; den += p1; den += p2; den += p3;
            const unsigned int* r0 = &hs[hh][s0 * 16];
            const unsigned int* r1 = &hs[hh][s1 * 16];
            const unsigned int* r2 = &hs[hh][s2 * 16];
            const unsigned int* r3 = &hs[hh][s3 * 16];
            int x0 = (s0 >> 1) & 3, x1 = (s1 >> 1) & 3;
            int x2 = (s2 >> 1) & 3, x3 = (s3 >> 1) & 3;
            EDGE_ACC(r0, x0, p0);
            EDGE_ACC(r1, x1, p1);
            EDGE_ACC(r2, x2, p2);
            EDGE_ACC(r3, x3, p3);
        }
        for (; e < end; ++e) {
            int   s0 = cs2[e];
            float w0 = ce2[e];
            float a0 = ssl[s0 * 4 + hh] + sd; a0 = (a0 > 0.f) ? a0 : 0.2f * a0;
            float p0 = __expf(a0 * w0);
            den += p0;
            const unsigned int* r0 = &hs[hh][s0 * 16];
            int x0 = (s0 >> 1) & 3;
            EDGE_ACC(r0, x0, p0);
        }

        float inv = 1.f / (den + 1e-16f);
        float s1 = 0.f, s2 = 0.f;
#pragma unroll
        for (int d = 0; d < 32; ++d) {
            float vv = fmaf(acc[d], inv, prm[hh * 32 + d]);
            acc[d] = vv;
            s1 += vv;
            s2 = fmaf(vv, vv, s2);
        }
        s1 += __shfl_xor(s1, 16, 64);
        s2 += __shfl_xor(s2, 16, 64);
        s1 += __shfl_xor(s1, 32, 64);
        s2 += __shfl_xor(s2, 32, 64);
        float mean = s1 * (1.f / 128.f);
        float var  = s2 * (1.f / 128.f) - mean * mean;
        float rstd = rsqrtf(var + 1e-5f);

        float* op = outb + (size_t)node * DIM + hh * 32;
#pragma unroll
        for (int d = 0; d < 32; d += 4) {
            int pd0 = 128 + hh * 32 + d, pb0 = 256 + hh * 32 + d;
            float y0 = (acc[d+0] - mean) * rstd * prm[pd0+0] + prm[pb0+0];
            float y1 = (acc[d+1] - mean) * rstd * prm[pd0+1] + prm[pb0+1];
            float y2 = (acc[d+2] - mean) * rstd * prm[pd0+2] + prm[pb0+2];
            float y3 = (acc[d+3] - mean) * rstd * prm[pd0+3] + prm[pb0+3];
            float4 o4;
            o4.x = (y0 > 0.f) ? y0 : expm1f(y0);
            o4.y = (y1 > 0.f) ? y1 : expm1f(y1);
            o4.z = (y2 > 0.f) ? y2 : expm1f(y2);
            o4.w = (y3 > 0.f) ? y3 : expm1f(y3);
            *(float4*)(op + d) = o4;
        }
    }
}

// ---------------------------------------------------------------------------
extern "C" void kernel_launch(void* const* d_in, const int* in_sizes, int n_in,
                              void* d_out, int out_size, void* d_ws, size_t ws_size,
                              hipStream_t stream)
{
    const float* x     = (const float*)d_in[0];
    const int*   ei    = (const int*)  d_in[1];
    const float* ew    = (const float*)d_in[2];
    const float* W     = (const float*)d_in[3];
    const float* asrc  = (const float*)d_in[4];
    const float* adst  = (const float*)d_in[5];
    const float* bias  = (const float*)d_in[6];
    const float* gamma = (const float*)d_in[7];
    const float* beta  = (const float*)d_in[8];
    float* out = (float*)d_out;

    char* ws = (char*)d_ws;
    unsigned short* h = (unsigned short*)ws;                 // 25 MB bf16
    size_t off = (size_t)NROWS * DIM * sizeof(unsigned short);
    unsigned short* wswz = (unsigned short*)(ws + off);      // 32 KB bf16 swizzled
    off += (size_t)DIM * DIM * sizeof(unsigned short);
    float* ssg = (float*)(ws + off);                         // 1.5 MB
    off += (size_t)NROWS * NH * sizeof(float);
    float* sdg = (float*)(ws + off);                         // 1.5 MB
    off += (size_t)NROWS * NH * sizeof(float);
    int* rp2 = (int*)(ws + off);
    off += (((NNODE + 1) * sizeof(int)) + 15) & ~(size_t)15;
    int* perm = (int*)(ws + off);
    off += (size_t)NNODE * sizeof(int);
    int* cs2 = (int*)(ws + off);
    off += (size_t)NE * sizeof(int);
    float* ce2 = (float*)(ws + off);
    off += (size_t)NE * sizeof(float);

    wswz_k<<<8, 512, 0, stream>>>(W, wswz);
    gemm_mfma_k<<<GEMM_BLOCKS + 64, 256, 0, stream>>>(
        x, wswz, asrc, adst, h, ssg, sdg, ei, ew, rp2, cs2, ce2, perm);
    agg_ln_k<<<BT, 1024, 0, stream>>>(h, ssg, sdg, rp2, cs2, ce2, perm,
                                      bias, gamma, beta, out);
}

// Round 17
// 70.655 us; speedup vs baseline: 1.4136x; 1.4115x over previous
//
#include <hip/hip_runtime.h>

#define BT    192
#define NNODE 512
#define DIM   128
#define NH    4
#define DH    32
#define NE    4096
#define NROWS (BT * NNODE)
#define GEMM_BLOCKS (NROWS / 128)   // 1536

typedef __attribute__((ext_vector_type(8))) short  short8b;
typedef __attribute__((ext_vector_type(4))) float  floatx4;
typedef __attribute__((ext_vector_type(8))) unsigned short ushort8;

__device__ inline unsigned short f2bf(float f) {
    unsigned int u = __float_as_uint(f);
    return (unsigned short)((u + 0x7FFFu + ((u >> 16) & 1u)) >> 16);
}
__device__ inline float bflo(unsigned int v) { return __uint_as_float(v << 16); }
__device__ inline float bfhi(unsigned int v) { return __uint_as_float(v & 0xFFFF0000u); }

__device__ inline short8b pack8(float4 a, float4 b) {
    short8b r;
    r[0] = (short)f2bf(a.x); r[1] = (short)f2bf(a.y);
    r[2] = (short)f2bf(a.z); r[3] = (short)f2bf(a.w);
    r[4] = (short)f2bf(b.x); r[5] = (short)f2bf(b.y);
    r[6] = (short)f2bf(b.z); r[7] = (short)f2bf(b.w);
    return r;
}

// ---------------------------------------------------------------------------
// K0: W pre-swizzle only (8 blocks x 512). Must precede the GEMM.
// ---------------------------------------------------------------------------
__global__ __launch_bounds__(512) void wswz_k(
    const float* __restrict__ W, unsigned short* __restrict__ wswz)
{
    int j = blockIdx.x * 512 + threadIdx.x;      // float4 index, 4096 total
    const float4* W4 = (const float4*)W;
    float4 wv = W4[j];
    int k = j >> 5, c4 = (j & 31) * 4;
    float vv[4] = { wv.x, wv.y, wv.z, wv.w };
#pragma unroll
    for (int e = 0; e < 4; ++e) {
        int col = c4 + e;
        int byte = col * 256 + ((2 * k) ^ ((col & 7) << 4));
        wswz[byte >> 1] = f2bf(vv[e]);
    }
}

// ---------------------------------------------------------------------------
// K1: bf16 MFMA GEMM + score epilogue (blocks 0..1535) + CSR build folded
// in as blocks 1536..1599 (runs concurrently; agg consumes both afterward).
// ---------------------------------------------------------------------------
__global__ __launch_bounds__(256) void gemm_mfma_k(
    const float* __restrict__ x, const unsigned short* __restrict__ wswz,
    const float* __restrict__ att_src, const float* __restrict__ att_dst,
    unsigned short* __restrict__ h, float* __restrict__ ssg,
    float* __restrict__ sdg,
    const int* __restrict__ ei, const float* __restrict__ ew,
    int* __restrict__ rp2, int* __restrict__ cs2,
    float* __restrict__ ce2, int* __restrict__ perm)
{
    __shared__ __align__(16) char sm[64 * 132 * 4];   // 33792 B
    __shared__ float att_f[256];
    int t = threadIdx.x;

    if (blockIdx.x >= GEMM_BLOCKS) {
        // ================= CSR build path (64 blocks, 256 threads) =========
        int* dsts   = (int*)sm;                 // 16384 B
        int* cnt    = (int*)(sm + 16384);       // 2048
        int* scn    = (int*)(sm + 18432);       // 2048
        int* nodeAt = (int*)(sm + 20480);       // 2048
        int* hist   = (int*)(sm + 22528);       // 1024
        int* hscan  = (int*)(sm + 23552);       // 1024
        int cb = blockIdx.x - GEMM_BLOCKS;
        int i0 = t, i1 = t + 256;

        for (int e = t; e < NE; e += 256) dsts[e] = ei[NE + e];
        cnt[i0] = 0; cnt[i1] = 0;
        hist[t] = 0;
        __syncthreads();
        for (int e = t; e < NE; e += 256) atomicAdd(&cnt[dsts[e]], 1);
        __syncthreads();

        int deg0 = cnt[i0], deg1 = cnt[i1];
        int b0 = (deg0 < 255) ? deg0 : 255;
        int b1 = (deg1 < 255) ? deg1 : 255;
        atomicAdd(&hist[b0], 1);
        atomicAdd(&hist[b1], 1);
        __syncthreads();
        hscan[t] = hist[t];
        __syncthreads();
        for (int o = 1; o < 256; o <<= 1) {
            int v = (t >= o) ? hscan[t - o] : 0;
            __syncthreads();
            hscan[t] += v;
            __syncthreads();
        }
        int off0 = 0, off1 = 0;
        for (int n = 0; n < i0; ++n) {
            int dn = cnt[n]; dn = (dn < 255) ? dn : 255;
            off0 += (dn == b0) ? 1 : 0;
        }
        for (int n = 0; n < i1; ++n) {
            int dn = cnt[n]; dn = (dn < 255) ? dn : 255;
            off1 += (dn == b1) ? 1 : 0;
        }
        int rank0 = hscan[b0] - hist[b0] + off0;
        int rank1 = hscan[b1] - hist[b1] + off1;
        nodeAt[rank0] = i0;
        nodeAt[rank1] = i1;
        __syncthreads();

        scn[i0] = cnt[nodeAt[i0]];
        scn[i1] = cnt[nodeAt[i1]];
        __syncthreads();
        for (int o = 1; o < NNODE; o <<= 1) {
            int v0 = (i0 >= o) ? scn[i0 - o] : 0;
            int v1 = (i1 >= o) ? scn[i1 - o] : 0;
            __syncthreads();
            scn[i0] += v0; scn[i1] += v1;
            __syncthreads();
        }
        if (cb == 0) {
            if (t == 0) rp2[0] = 0;
            rp2[i0 + 1] = scn[i0];
            rp2[i1 + 1] = scn[i1];
            perm[i0] = nodeAt[i0];
            perm[i1] = nodeAt[i1];
        }
        __syncthreads();

        int wave = t >> 6, lane = t & 63;
#pragma unroll
        for (int rr = 0; rr < 2; ++rr) {
            int r = cb * 8 + rr * 4 + wave;
            int node = nodeAt[r];
            int pos = scn[r] - cnt[node];
            for (int c = 0; c < NE; c += 64) {
                int e = c + lane;
                int d = dsts[e];
                unsigned long long mask = __ballot(d == node);
                if (d == node) {
                    int ofs = __popcll(mask & ((1ull << lane) - 1ull));
                    cs2[pos + ofs] = ei[e];
                    ce2[pos + ofs] = ew[e];
                }
                pos += __popcll(mask);
            }
        }
        return;
    }

    // ================= GEMM path (blocks 0..1535, unchanged) ===============
    if (t < 128) att_f[t] = att_src[(t & 3) * 32 + (t >> 2)];
    else         att_f[t] = att_dst[(t & 3) * 32 + ((t - 128) >> 2)];
    {
        const uint4* g = (const uint4*)wswz;
        uint4* ld = (uint4*)sm;
#pragma unroll
        for (int i = 0; i < 8; ++i) ld[t + i * 256] = g[t + i * 256];
    }
    int w = t >> 6, l = t & 63, lr = l & 15, lk = l >> 4;
    size_t base = (size_t)blockIdx.x * 128;
    const float* xA = x + (base + (size_t)w * 16 + lr) * DIM;
    const float* xB = xA + 64 * DIM;

    floatx4 accA[8], accB[8];
#pragma unroll
    for (int n = 0; n < 8; ++n) {
        accA[n] = (floatx4){0.f, 0.f, 0.f, 0.f};
        accB[n] = (floatx4){0.f, 0.f, 0.f, 0.f};
    }
    __syncthreads();

#pragma unroll
    for (int kk = 0; kk < 4; ++kk) {
        int k0 = kk * 32 + lk * 8;
        float4 a0 = *(const float4*)(xA + k0);
        float4 a1 = *(const float4*)(xA + k0 + 4);
        float4 b0 = *(const float4*)(xB + k0);
        float4 b1 = *(const float4*)(xB + k0 + 4);
        short8b av = pack8(a0, a1);
        short8b bv = pack8(b0, b1);
        int c = kk * 4 + lk;
#pragma unroll
        for (int n = 0; n < 8; ++n) {
            int col = n * 16 + lr;
            short8b bf = *(const short8b*)(sm + col * 256 + ((c ^ (col & 7)) << 4));
            accA[n] = __builtin_amdgcn_mfma_f32_16x16x32_bf16(av, bf, accA[n], 0, 0, 0);
            accB[n] = __builtin_amdgcn_mfma_f32_16x16x32_bf16(bv, bf, accB[n], 0, 0, 0);
        }
    }

    float* Ct = (float*)sm;
    unsigned short* hbase = h + base * DIM;
    int sr = t >> 2, sq = t & 3;

    // pass A: rows 0..63
    __syncthreads();
#pragma unroll
    for (int n = 0; n < 8; ++n)
#pragma unroll
        for (int j = 0; j < 4; ++j)
            Ct[(w * 16 + lk * 4 + j) * 132 + n * 16 + lr] = accA[n][j];
    __syncthreads();
#pragma unroll
    for (int i = 0; i < 4; ++i) {
        int chunk = t + i * 256;
        int row = chunk >> 4, cc = chunk & 15;
        const float* cp = Ct + row * 132 + cc * 8;
        ushort8 v;
#pragma unroll
        for (int e = 0; e < 8; ++e) v[e] = f2bf(cp[e]);
        *(ushort8*)(hbase + row * DIM + cc * 8) = v;
    }
    {
        const float* cp = Ct + sr * 132 + sq * 32;
        float ps = 0.f, pd = 0.f;
#pragma unroll
        for (int j = 0; j < 32; j += 4) {
            float4 cv = *(const float4*)(cp + j);
            ps = fmaf(cv.x, att_f[(j+0)*4 + sq], ps);
            ps = fmaf(cv.y, att_f[(j+1)*4 + sq], ps);
            ps = fmaf(cv.z, att_f[(j+2)*4 + sq], ps);
            ps = fmaf(cv.w, att_f[(j+3)*4 + sq], ps);
            pd = fmaf(cv.x, att_f[128 + (j+0)*4 + sq], pd);
            pd = fmaf(cv.y, att_f[128 + (j+1)*4 + sq], pd);
            pd = fmaf(cv.z, att_f[128 + (j+2)*4 + sq], pd);
            pd = fmaf(cv.w, att_f[128 + (j+3)*4 + sq], pd);
        }
        size_t grow = base + sr;
        ssg[grow * 4 + sq] = ps;
        sdg[grow * 4 + sq] = pd;
    }

    // pass B: rows 64..127
    __syncthreads();
#pragma unroll
    for (int n = 0; n < 8; ++n)
#pragma unroll
        for (int j = 0; j < 4; ++j)
            Ct[(w * 16 + lk * 4 + j) * 132 + n * 16 + lr] = accB[n][j];
    __syncthreads();
#pragma unroll
    for (int i = 0; i < 4; ++i) {
        int chunk = t + i * 256;
        int row = chunk >> 4, cc = chunk & 15;
        const float* cp = Ct + row * 132 + cc * 8;
        ushort8 v;
#pragma unroll
        for (int e = 0; e < 8; ++e) v[e] = f2bf(cp[e]);
        *(ushort8*)(hbase + (64 + row) * DIM + cc * 8) = v;
    }
    {
        const float* cp = Ct + sr * 132 + sq * 32;
        float ps = 0.f, pd = 0.f;
#pragma unroll
        for (int j = 0; j < 32; j += 4) {
            float4 cv = *(const float4*)(cp + j);
            ps = fmaf(cv.x, att_f[(j+0)*4 + sq], ps);
            ps = fmaf(cv.y, att_f[(j+1)*4 + sq], ps);
            ps = fmaf(cv.z, att_f[(j+2)*4 + sq], ps);
            ps = fmaf(cv.w, att_f[(j+3)*4 + sq], ps);
            pd = fmaf(cv.x, att_f[128 + (j+0)*4 + sq], pd);
            pd = fmaf(cv.y, att_f[128 + (j+1)*4 + sq], pd);
            pd = fmaf(cv.z, att_f[128 + (j+2)*4 + sq], pd);
            pd = fmaf(cv.w, att_f[128 + (j+3)*4 + sq], pd);
        }
        size_t grow = base + 64 + sr;
        ssg[grow * 4 + sq] = ps;
        sdg[grow * 4 + sq] = pd;
    }
}

// ---------------------------------------------------------------------------
// K2: FULLY FUSED gather-agg + softmax-normalize + bias + LayerNorm + ELU.
// Exact r13 structure (verified best: 60 VGPR, no spill): one block per bt,
// 1024 threads, h slice staged once in 128 KB LDS as 4 per-head arrays
// [512][16 u32] chunk-swizzled; lane map l = head*16 + rl -> LN reduce =
// shfl_xor(16)+shfl_xor(32); ranks g and 511-g per thread (degree-balanced);
// scattered float4 writes (free at this HBM util); 2-WAY edge unroll
// (4-way spills at the compiler's fixed 64-VGPR budget for 1024-thr blocks
// — r14/r15 evidence).
// ---------------------------------------------------------------------------
__global__ __launch_bounds__(1024) void agg_ln_k(
    const unsigned short* __restrict__ h,
    const float* __restrict__ ssg, const float* __restrict__ sdg,
    const int* __restrict__ rp2, const int* __restrict__ cs2,
    const float* __restrict__ ce2, const int* __restrict__ perm,
    const float* __restrict__ bias, const float* __restrict__ gamma,
    const float* __restrict__ beta, float* __restrict__ out)
{
    __shared__ unsigned int hs[NH][NNODE * 16];   // 131072 B
    __shared__ float ssl[NNODE * NH];             // 8192 B
    __shared__ float prm[384];                    // bias | gamma | beta
    int t  = threadIdx.x;
    int bt = blockIdx.x;

    const uint4* hg = (const uint4*)(h + (size_t)bt * NNODE * DIM);
    for (int i = t; i < NNODE * 16; i += 1024) {
        int n = i >> 4, c = i & 15, hh = c >> 2, j = c & 3;
        uint4 v = hg[i];
        int js = j ^ ((n >> 1) & 3);
        *(uint4*)&hs[hh][n * 16 + js * 4] = v;
    }
    const float* ssgb = ssg + (size_t)bt * NNODE * NH;
    for (int i = t; i < NNODE * NH; i += 1024) ssl[i] = ssgb[i];
    if (t < 384) prm[t] = (t < 128) ? bias[t] : (t < 256) ? gamma[t - 128] : beta[t - 256];
    __syncthreads();

    int l  = t & 63, w = t >> 6;
    int hh = l >> 4, rl = l & 15;
    int g  = w * 16 + rl;                          // 0..255
    const float* sdgb = sdg + (size_t)bt * NNODE * NH;
    float* outb = out + (size_t)bt * NNODE * DIM;

#pragma unroll
    for (int pi = 0; pi < 2; ++pi) {
        int rank = pi ? (511 - g) : g;
        int node = perm[rank];
        int beg = rp2[rank], end = rp2[rank + 1];
        float sd = sdgb[node * 4 + hh];

        float acc[32];
#pragma unroll
        for (int d = 0; d < 32; ++d) acc[d] = 0.f;
        float den = 0.f;

        int e = beg;
        for (; e + 2 <= end; e += 2) {
            int   s0 = cs2[e],   s1 = cs2[e + 1];
            float w0 = ce2[e],   w1 = ce2[e + 1];
            float a0 = ssl[s0 * 4 + hh] + sd; a0 = (a0 > 0.f) ? a0 : 0.2f * a0;
            float a1 = ssl[s1 * 4 + hh] + sd; a1 = (a1 > 0.f) ? a1 : 0.2f * a1;
            float p0 = __expf(a0 * w0);
            float p1 = __expf(a1 * w1);
            den += p0; den += p1;
            const unsigned int* r0 = &hs[hh][s0 * 16];
            const unsigned int* r1 = &hs[hh][s1 * 16];
            int sx0 = (s0 >> 1) & 3, sx1 = (s1 >> 1) & 3;
#pragma unroll
            for (int j = 0; j < 4; ++j) {
                uint4 v0 = *(const uint4*)&r0[(j ^ sx0) * 4];
                uint4 v1 = *(const uint4*)&r1[(j ^ sx1) * 4];
                int d0 = j * 8;
                acc[d0+0] = fmaf(p0, bflo(v0.x), acc[d0+0]);
                acc[d0+1] = fmaf(p0, bfhi(v0.x), acc[d0+1]);
                acc[d0+2] = fmaf(p0, bflo(v0.y), acc[d0+2]);
                acc[d0+3] = fmaf(p0, bfhi(v0.y), acc[d0+3]);
                acc[d0+4] = fmaf(p0, bflo(v0.z), acc[d0+4]);
                acc[d0+5] = fmaf(p0, bfhi(v0.z), acc[d0+5]);
                acc[d0+6] = fmaf(p0, bflo(v0.w), acc[d0+6]);
                acc[d0+7] = fmaf(p0, bfhi(v0.w), acc[d0+7]);
                acc[d0+0] = fmaf(p1, bflo(v1.x), acc[d0+0]);
                acc[d0+1] = fmaf(p1, bfhi(v1.x), acc[d0+1]);
                acc[d0+2] = fmaf(p1, bflo(v1.y), acc[d0+2]);
                acc[d0+3] = fmaf(p1, bfhi(v1.y), acc[d0+3]);
                acc[d0+4] = fmaf(p1, bflo(v1.z), acc[d0+4]);
                acc[d0+5] = fmaf(p1, bfhi(v1.z), acc[d0+5]);
                acc[d0+6] = fmaf(p1, bflo(v1.w), acc[d0+6]);
                acc[d0+7] = fmaf(p1, bfhi(v1.w), acc[d0+7]);
            }
        }
        if (e < end) {
            int   s0 = cs2[e];
            float w0 = ce2[e];
            float a0 = ssl[s0 * 4 + hh] + sd; a0 = (a0 > 0.f) ? a0 : 0.2f * a0;
            float p0 = __expf(a0 * w0);
            den += p0;
            const unsigned int* r0 = &hs[hh][s0 * 16];
            int sx0 = (s0 >> 1) & 3;
#pragma unroll
            for (int j = 0; j < 4; ++j) {
                uint4 v0 = *(const uint4*)&r0[(j ^ sx0) * 4];
                int d0 = j * 8;
                acc[d0+0] = fmaf(p0, bflo(v0.x), acc[d0+0]);
                acc[d0+1] = fmaf(p0, bfhi(v0.x), acc[d0+1]);
                acc[d0+2] = fmaf(p0, bflo(v0.y), acc[d0+2]);
                acc[d0+3] = fmaf(p0, bfhi(v0.y), acc[d0+3]);
                acc[d0+4] = fmaf(p0, bflo(v0.z), acc[d0+4]);
                acc[d0+5] = fmaf(p0, bfhi(v0.z), acc[d0+5]);
                acc[d0+6] = fmaf(p0, bflo(v0.w), acc[d0+6]);
                acc[d0+7] = fmaf(p0, bfhi(v0.w), acc[d0+7]);
            }
        }

        // normalize + bias; partial LN sums
        float inv = 1.f / (den + 1e-16f);
        float s1 = 0.f, s2 = 0.f;
#pragma unroll
        for (int d = 0; d < 32; ++d) {
            float vv = fmaf(acc[d], inv, prm[hh * 32 + d]);
            acc[d] = vv;
            s1 += vv;
            s2 = fmaf(vv, vv, s2);
        }
        // reduce across the node's 4 head-lanes (l, l^16, l^32, l^48)
        s1 += __shfl_xor(s1, 16, 64);
        s2 += __shfl_xor(s2, 16, 64);
        s1 += __shfl_xor(s1, 32, 64);
        s2 += __shfl_xor(s2, 32, 64);
        float mean = s1 * (1.f / 128.f);
        float var  = s2 * (1.f / 128.f) - mean * mean;
        float rstd = rsqrtf(var + 1e-5f);

        float* op = outb + (size_t)node * DIM + hh * 32;
#pragma unroll
        for (int d = 0; d < 32; d += 4) {
            int pd0 = 128 + hh * 32 + d, pb0 = 256 + hh * 32 + d;
            float y0 = (acc[d+0] - mean) * rstd * prm[pd0+0] + prm[pb0+0];
            float y1 = (acc[d+1] - mean) * rstd * prm[pd0+1] + prm[pb0+1];
            float y2 = (acc[d+2] - mean) * rstd * prm[pd0+2] + prm[pb0+2];
            float y3 = (acc[d+3] - mean) * rstd * prm[pd0+3] + prm[pb0+3];
            float4 o4;
            o4.x = (y0 > 0.f) ? y0 : expm1f(y0);
            o4.y = (y1 > 0.f) ? y1 : expm1f(y1);
            o4.z = (y2 > 0.f) ? y2 : expm1f(y2);
            o4.w = (y3 > 0.f) ? y3 : expm1f(y3);
            *(float4*)(op + d) = o4;
        }
    }
}

// ---------------------------------------------------------------------------
extern "C" void kernel_launch(void* const* d_in, const int* in_sizes, int n_in,
                              void* d_out, int out_size, void* d_ws, size_t ws_size,
                              hipStream_t stream)
{
    const float* x     = (const float*)d_in[0];
    const int*   ei    = (const int*)  d_in[1];
    const float* ew    = (const float*)d_in[2];
    const float* W     = (const float*)d_in[3];
    const float* asrc  = (const float*)d_in[4];
    const float* adst  = (const float*)d_in[5];
    const float* bias  = (const float*)d_in[6];
    const float* gamma = (const float*)d_in[7];
    const float* beta  = (const float*)d_in[8];
    float* out = (float*)d_out;

    char* ws = (char*)d_ws;
    unsigned short* h = (unsigned short*)ws;                 // 25 MB bf16
    size_t off = (size_t)NROWS * DIM * sizeof(unsigned short);
    unsigned short* wswz = (unsigned short*)(ws + off);      // 32 KB bf16 swizzled
    off += (size_t)DIM * DIM * sizeof(unsigned short);
    float* ssg = (float*)(ws + off);                         // 1.5 MB
    off += (size_t)NROWS * NH * sizeof(float);
    float* sdg = (float*)(ws + off);                         // 1.5 MB
    off += (size_t)NROWS * NH * sizeof(float);
    int* rp2 = (int*)(ws + off);
    off += (((NNODE + 1) * sizeof(int)) + 15) & ~(size_t)15;
    int* perm = (int*)(ws + off);
    off += (size_t)NNODE * sizeof(int);
    int* cs2 = (int*)(ws + off);
    off += (size_t)NE * sizeof(int);
    float* ce2 = (float*)(ws + off);
    off += (size_t)NE * sizeof(float);

    wswz_k<<<8, 512, 0, stream>>>(W, wswz);
    gemm_mfma_k<<<GEMM_BLOCKS + 64, 256, 0, stream>>>(
        x, wswz, asrc, adst, h, ssg, sdg, ei, ew, rp2, cs2, ce2, perm);
    agg_ln_k<<<BT, 1024, 0, stream>>>(h, ssg, sdg, rp2, cs2, ce2, perm,
                                      bias, gamma, beta, out);
}